// Round 6
// baseline (494.047 us; speedup 1.0000x reference)
//
#include <hip/hip_runtime.h>

#define T_ 512
#define B_ 2048
#define NB_ 8                 // batches per block; grid = B_/NB_ = 256 = 1 block/CU
#define TANH_K (-2.8853900817779268f)   // -2*log2(e)

// LDS layout (dword units). Two ping-pong buffers, each 8 batches x 512 rows x
// 10 bf16 cols (20 B/row), SoA-split for 8B alignment:
//   A[buf][b][t] : uint2 = cols 0-3   base AOFF, idx ((buf*8+b)*512+t)*2
//   B[buf][b][t] : u32   = cols 4-5   base BOFF, idx  (buf*8+b)*512+t
//   C[buf][b][t] : uint2 = cols 6-9   base COFF, idx ((buf*8+b)*512+t)*2
// total = 16384 + 8192 + 16384 = 40960 dwords = 163840 B (gfx950 LDS max).
// dir 0 owns cols 0-4 (A pair + B.lo), dir 1 owns cols 5-9 (B.hi + C pair).
#define AOFF 0
#define BOFF 16384
#define COFF 24576

// DPP ctrl encodings (gfx9/CDNA)
#define DPP_ROW_ROR8        0x128   // lane^8  within 16-lane row
#define DPP_ROW_MIRROR      0x140   // lane^15 within 16-lane row
#define DPP_ROW_HALF_MIRROR 0x141   // lane^7  within 16-lane row

__device__ __forceinline__ float sig2(float y) {           // 1/(1+exp2(y))
  return __builtin_amdgcn_rcpf(1.0f + __builtin_amdgcn_exp2f(y));
}

template<int CTRL>
__device__ __forceinline__ float dppf(float v) {
  return __int_as_float(__builtin_amdgcn_mov_dpp(__float_as_int(v), CTRL, 0xF, 0xF, true));
}

__device__ __forceinline__ float lo16(unsigned d) { return __int_as_float((int)(d << 16)); }
__device__ __forceinline__ float hi16(unsigned d) { return __int_as_float((int)(d & 0xFFFF0000u)); }

__device__ __forceinline__ unsigned cvtpk(float lo, float hi) {   // 2xf32 -> packed bf16 (RNE)
  unsigned r;
  asm("v_cvt_pk_bf16_f32 %0, %1, %2" : "=v"(r) : "v"(lo), "v"(hi));
  return r;
}

struct Row5 { uint2 a; unsigned b; uint2 c; };
struct Pre2 { float a, b; };

__device__ __forceinline__ Row5 ld_row(const unsigned* lds, int ai, int bi, int ci) {
  Row5 r;
  r.a = *(const uint2*)(lds + ai);
  r.b = lds[bi];
  r.c = *(const uint2*)(lds + ci);
  return r;
}

// Dual input projection: row A (gate g of unit p) and row B (gate g of unit 4).
__device__ __forceinline__ Pre2 proj_dual(const Row5& r,
    const float* wiA, const float* wiB, float bbA, float bbB) {
  const float x0=lo16(r.a.x), x1=hi16(r.a.x), x2=lo16(r.a.y), x3=hi16(r.a.y);
  const float x4=lo16(r.b),   x5=hi16(r.b);
  const float x6=lo16(r.c.x), x7=hi16(r.c.x), x8=lo16(r.c.y), x9=hi16(r.c.y);
  float a0=bbA, a1=0.f, b0=bbB, b1=0.f;
  a0=fmaf(wiA[0],x0,a0); a1=fmaf(wiA[1],x1,a1);
  a0=fmaf(wiA[2],x2,a0); a1=fmaf(wiA[3],x3,a1);
  a0=fmaf(wiA[4],x4,a0); a1=fmaf(wiA[5],x5,a1);
  a0=fmaf(wiA[6],x6,a0); a1=fmaf(wiA[7],x7,a1);
  a0=fmaf(wiA[8],x8,a0); a1=fmaf(wiA[9],x9,a1);
  b0=fmaf(wiB[0],x0,b0); b1=fmaf(wiB[1],x1,b1);
  b0=fmaf(wiB[2],x2,b0); b1=fmaf(wiB[3],x3,b1);
  b0=fmaf(wiB[4],x4,b0); b1=fmaf(wiB[5],x5,b1);
  b0=fmaf(wiB[6],x6,b0); b1=fmaf(wiB[7],x7,b1);
  b0=fmaf(wiB[8],x8,b0); b1=fmaf(wiB[9],x9,b1);
  Pre2 o; o.a = a0+a1; o.b = b0+b1; return o;
}

// One recurrent step for a 16-lane chain. Lane = 4p+g: row A = gate g of unit p,
// row B = gate g of unit 4 (redundant/identical in every quad).
// h slots: h0s=h_p, h1s=h_{p^1}, h2s=h_{p^2}, h3s=h_{p^3}; h4 lane-local.
__device__ __forceinline__ void recur_dual(float preA, float preB,
    const float* wsA, const float* wsB, float vm, float va,
    float& c, float& c4, float& h0s, float& h1s, float& h2s, float& h3s, float& h4)
{
  const float a0 = fmaf(wsA[1], h1s, fmaf(wsA[0], h0s, preA));
  const float a1 = fmaf(wsA[4], h4,  fmaf(wsA[3], h3s, wsA[2] * h2s));
  const float b0 = fmaf(wsB[1], h1s, fmaf(wsB[0], h0s, preB));
  const float b1 = fmaf(wsB[4], h4,  fmaf(wsB[3], h3s, wsB[2] * h2s));
  const float vA = fmaf(sig2(a0 + a1), vm, va);   // sigmoid, or tanh = 2s-1
  const float vB = fmaf(sig2(b0 + b1), vm, va);
  const float ivA = dppf<0x00>(vA), fvA = dppf<0x55>(vA), gvA = dppf<0xAA>(vA), ovA = dppf<0xFF>(vA);
  const float ivB = dppf<0x00>(vB), fvB = dppf<0x55>(vB), gvB = dppf<0xAA>(vB), ovB = dppf<0xFF>(vB);
  c  = fmaf(fvA, c,  ivA * gvA);
  c4 = fmaf(fvB, c4, ivB * gvB);
  const float h = fmaf(sig2(c * TANH_K), 2.0f * ovA, -ovA);   // ov*tanh(c)
  h4            = fmaf(sig2(c4 * TANH_K), 2.0f * ovB, -ovB);
  h0s = h;
  h1s = dppf<DPP_ROW_HALF_MIRROR>(h);   // lane^7  -> unit p^1
  h2s = dppf<DPP_ROW_ROR8>(h);          // lane^8  -> unit p^2
  h3s = dppf<DPP_ROW_MIRROR>(h);        // lane^15 -> unit p^3
}

__device__ __forceinline__ void emit_row(unsigned* lds, int dpair, int dsh, int dd,
    float h0s, float h1s, float h2s, float h3s, float h4) {
  unsigned v0, v1, vs;
  if (dd) { v0 = cvtpk(h1s, h2s); v1 = cvtpk(h3s, h4);  vs = cvtpk(h0s, h0s); }
  else    { v0 = cvtpk(h0s, h1s); v1 = cvtpk(h2s, h3s); vs = cvtpk(h4, h4); }
  uint2 pr; pr.x = v0; pr.y = v1;
  *(uint2*)(lds + dpair) = pr;                       // A pair (d0) or C pair (d1)
  ((unsigned short*)lds)[dsh] = (unsigned short)vs;  // B.lo (d0) or B.hi (d1)
}

// LDS-input scan (layers 1..4), 4-slot software pipeline.
template<bool STORE>
__device__ __forceinline__ void scan_lds(unsigned* lds,
    int sab, int sbb, int scb, int sA, int sB,
    int dpair, int dsh, int dd, bool doStore,
    const float* wiA, const float* wiB, float bbA, float bbB,
    const float* wsA, const float* wsB, float vm, float va,
    float& c, float& c4, float& h0s, float& h1s, float& h2s, float& h3s, float& h4)
{
  Row5 p_[4]; Pre2 pre[4];
  #pragma unroll
  for (int k = 0; k < 4; ++k) { p_[k] = ld_row(lds, sab, sbb, scb); sab += sA; sbb += sB; scb += sA; }
  #pragma unroll
  for (int k = 0; k < 4; ++k) pre[k] = proj_dual(p_[k], wiA, wiB, bbA, bbB);
  #pragma unroll
  for (int k = 0; k < 4; ++k) { p_[k] = ld_row(lds, sab, sbb, scb); sab += sA; sbb += sB; scb += sA; }
  c = 0.f; c4 = 0.f; h0s = h1s = h2s = h3s = h4 = 0.f;
  for (int tt = 0; tt + 8 < T_; tt += 4) {
    #pragma unroll
    for (int j = 0; j < 4; ++j) {
      recur_dual(pre[j].a, pre[j].b, wsA, wsB, vm, va, c, c4, h0s, h1s, h2s, h3s, h4);
      if constexpr (STORE) {
        if (doStore) emit_row(lds, dpair, dsh, dd, h0s, h1s, h2s, h3s, h4);
        dpair += sA; dsh += 2 * sB;
      }
      pre[j] = proj_dual(p_[j], wiA, wiB, bbA, bbB);
      p_[j] = ld_row(lds, sab, sbb, scb); sab += sA; sbb += sB; scb += sA;
    }
  }
  #pragma unroll
  for (int j = 0; j < 4; ++j) {     // steps T-8..T-5
    recur_dual(pre[j].a, pre[j].b, wsA, wsB, vm, va, c, c4, h0s, h1s, h2s, h3s, h4);
    if constexpr (STORE) {
      if (doStore) emit_row(lds, dpair, dsh, dd, h0s, h1s, h2s, h3s, h4);
      dpair += sA; dsh += 2 * sB;
    }
    pre[j] = proj_dual(p_[j], wiA, wiB, bbA, bbB);
  }
  #pragma unroll
  for (int j = 0; j < 4; ++j) {     // steps T-4..T-1
    recur_dual(pre[j].a, pre[j].b, wsA, wsB, vm, va, c, c4, h0s, h1s, h2s, h3s, h4);
    if constexpr (STORE) {
      if (doStore) emit_row(lds, dpair, dsh, dd, h0s, h1s, h2s, h3s, h4);
      dpair += sA; dsh += 2 * sB;
    }
  }
}

// Layer-0 scan: f32 global input (width 2), 8-deep prefetch, stores to LDS buf0.
__device__ __forceinline__ void scan0(const float* src, int sstep, unsigned* lds,
    int dpair, int dsh, int sA, int sB, int dd, bool doStore,
    const float* wiA, const float* wiB, float bbA, float bbB,
    const float* wsA, const float* wsB, float vm, float va)
{
  float2 p_[8]; Pre2 pre[8];
  #pragma unroll
  for (int k = 0; k < 8; ++k) p_[k] = *(const float2*)(src + k * sstep);
  #pragma unroll
  for (int k = 0; k < 8; ++k) {
    pre[k].a = fmaf(wiA[1], p_[k].y, fmaf(wiA[0], p_[k].x, bbA));
    pre[k].b = fmaf(wiB[1], p_[k].y, fmaf(wiB[0], p_[k].x, bbB));
  }
  #pragma unroll
  for (int k = 0; k < 8; ++k) p_[k] = *(const float2*)(src + (8 + k) * sstep);
  const float* lp = src + 16 * sstep;
  float c = 0.f, c4 = 0.f, h0s = 0.f, h1s = 0.f, h2s = 0.f, h3s = 0.f, h4 = 0.f;
  for (int tt = 0; tt + 16 < T_; tt += 8) {
    #pragma unroll
    for (int j = 0; j < 8; ++j) {
      recur_dual(pre[j].a, pre[j].b, wsA, wsB, vm, va, c, c4, h0s, h1s, h2s, h3s, h4);
      if (doStore) emit_row(lds, dpair, dsh, dd, h0s, h1s, h2s, h3s, h4);
      dpair += sA; dsh += 2 * sB;
      pre[j].a = fmaf(wiA[1], p_[j].y, fmaf(wiA[0], p_[j].x, bbA));
      pre[j].b = fmaf(wiB[1], p_[j].y, fmaf(wiB[0], p_[j].x, bbB));
      p_[j] = *(const float2*)lp; lp += sstep;
    }
  }
  #pragma unroll
  for (int j = 0; j < 8; ++j) {
    recur_dual(pre[j].a, pre[j].b, wsA, wsB, vm, va, c, c4, h0s, h1s, h2s, h3s, h4);
    if (doStore) emit_row(lds, dpair, dsh, dd, h0s, h1s, h2s, h3s, h4);
    dpair += sA; dsh += 2 * sB;
    pre[j].a = fmaf(wiA[1], p_[j].y, fmaf(wiA[0], p_[j].x, bbA));
    pre[j].b = fmaf(wiB[1], p_[j].y, fmaf(wiB[0], p_[j].x, bbB));
  }
  #pragma unroll
  for (int j = 0; j < 8; ++j) {
    recur_dual(pre[j].a, pre[j].b, wsA, wsB, vm, va, c, c4, h0s, h1s, h2s, h3s, h4);
    if (doStore) emit_row(lds, dpair, dsh, dd, h0s, h1s, h2s, h3s, h4);
    dpair += sA; dsh += 2 * sB;
  }
}

__global__ __launch_bounds__(256) void lstm_all(
    const float* __restrict__ x, const float* __restrict__ Wih0,
    const float* __restrict__ Wih, const float* __restrict__ Whh,
    const float* __restrict__ bias, const float* __restrict__ Wfc,
    const float* __restrict__ bfc, float* __restrict__ out)
{
  __shared__ __align__(16) unsigned lds[40960];   // 163840 B = gfx950 LDS max

  const int tid  = threadIdx.x;
  const int lane = tid & 63;
  const int wave = tid >> 6;
  const int cw   = lane >> 4;          // chain within wave: 0..3
  const int sub  = lane & 15;
  const int p    = sub >> 2;           // hidden unit (quad) 0..3
  const int g    = sub & 3;            // gate 0=i,1=f,2=g,3=o
  const int rowA = g * 5 + p;
  const int rowB = g * 5 + 4;
  const int ch   = wave * 4 + cw;      // chain in block: 0..15
  const int dd   = ch & 1;             // direction
  const int blb  = ch >> 1;            // block-local batch 0..7
  const int babs = blockIdx.x * NB_ + blb;   // grid exact: always < B_

  const int i1 = p ^ 1, i2 = p ^ 2, i3 = p ^ 3;

  const float LOG2E = 1.4426950408889634f;
  const float km = (g == 2) ? (-2.0f * LOG2E) : (-LOG2E);
  const float vm = (g == 2) ? 2.0f : 1.0f;
  const float va = (g == 2) ? -1.0f : 0.0f;

  const bool doStore = (sub == 0);
  const int t0   = dd ? (T_ - 1) : 0;
  const int sA   = dd ? -2 : 2;        // A/C dword step per t
  const int sB   = dd ? -1 : 1;        // B dword step per t

  float wsA[5], wsB[5], bbA, bbB;
  float c, c4, h0s, h1s, h2s, h3s, h4;

  // ---------------- layer 0 (f32 x, width 2) -> buf0 ----------------
  {
    float wiA2[2], wiB2[2];
    const float* W0 = Wih0 + (size_t)dd * 20 * 2;
    wiA2[0] = W0[rowA*2+0] * km; wiA2[1] = W0[rowA*2+1] * km;
    wiB2[0] = W0[rowB*2+0] * km; wiB2[1] = W0[rowB*2+1] * km;
    const float* Whp = Whh + (size_t)dd * 20 * 5;
    wsA[0]=Whp[rowA*5+p]*km; wsA[1]=Whp[rowA*5+i1]*km; wsA[2]=Whp[rowA*5+i2]*km;
    wsA[3]=Whp[rowA*5+i3]*km; wsA[4]=Whp[rowA*5+4]*km;
    wsB[0]=Whp[rowB*5+p]*km; wsB[1]=Whp[rowB*5+i1]*km; wsB[2]=Whp[rowB*5+i2]*km;
    wsB[3]=Whp[rowB*5+i3]*km; wsB[4]=Whp[rowB*5+4]*km;
    bbA = bias[(size_t)dd * 20 + rowA] * km;
    bbB = bias[(size_t)dd * 20 + rowB] * km;
    const int dstbase = blb * T_ + t0;                    // buf0
    const int dpair = dd ? (COFF + dstbase * 2) : (dstbase * 2);
    const int dsh   = (BOFF + dstbase) * 2 + dd;
    const float* src0 = x + ((size_t)babs * T_ + t0) * 2;
    scan0(src0, dd ? -2 : 2, lds, dpair, dsh, sA, sB, dd, doStore,
          wiA2, wiB2, bbA, bbB, wsA, wsB, vm, va);
  }
  __syncthreads();

  // ---------------- layers 1..3 ----------------
  for (int l = 1; l < 4; ++l) {
    float wiA[10], wiB[10];
    const float* Wip = Wih + ((size_t)(l - 1) * 2 + dd) * 20 * 10;
    #pragma unroll
    for (int k = 0; k < 10; ++k) { wiA[k] = Wip[rowA*10+k] * km; wiB[k] = Wip[rowB*10+k] * km; }
    const float* Whp = Whh + ((size_t)l * 2 + dd) * 20 * 5;
    wsA[0]=Whp[rowA*5+p]*km; wsA[1]=Whp[rowA*5+i1]*km; wsA[2]=Whp[rowA*5+i2]*km;
    wsA[3]=Whp[rowA*5+i3]*km; wsA[4]=Whp[rowA*5+4]*km;
    wsB[0]=Whp[rowB*5+p]*km; wsB[1]=Whp[rowB*5+i1]*km; wsB[2]=Whp[rowB*5+i2]*km;
    wsB[3]=Whp[rowB*5+i3]*km; wsB[4]=Whp[rowB*5+4]*km;
    bbA = bias[((size_t)l * 2 + dd) * 20 + rowA] * km;
    bbB = bias[((size_t)l * 2 + dd) * 20 + rowB] * km;
    const int sbuf = (l + 1) & 1, dbuf = l & 1;           // L1:0->1 L2:1->0 L3:0->1
    const int srcbase = (sbuf * NB_ + blb) * T_ + t0;
    const int dstbase = (dbuf * NB_ + blb) * T_ + t0;
    const int dpair = dd ? (COFF + dstbase * 2) : (dstbase * 2);
    const int dsh   = (BOFF + dstbase) * 2 + dd;
    scan_lds<true>(lds, srcbase * 2, BOFF + srcbase, COFF + srcbase * 2, sA, sB,
                   dpair, dsh, dd, doStore,
                   wiA, wiB, bbA, bbB, wsA, wsB, vm, va,
                   c, c4, h0s, h1s, h2s, h3s, h4);
    __syncthreads();
  }

  // ---------------- layer 4 (reads buf1): fwd full scan, bwd 1 step ----------------
  {
    float wiA[10], wiB[10];
    const float* Wip = Wih + ((size_t)3 * 2 + dd) * 20 * 10;
    #pragma unroll
    for (int k = 0; k < 10; ++k) { wiA[k] = Wip[rowA*10+k] * km; wiB[k] = Wip[rowB*10+k] * km; }
    const float* Whp = Whh + ((size_t)4 * 2 + dd) * 20 * 5;
    wsA[0]=Whp[rowA*5+p]*km; wsA[1]=Whp[rowA*5+i1]*km; wsA[2]=Whp[rowA*5+i2]*km;
    wsA[3]=Whp[rowA*5+i3]*km; wsA[4]=Whp[rowA*5+4]*km;
    wsB[0]=Whp[rowB*5+p]*km; wsB[1]=Whp[rowB*5+i1]*km; wsB[2]=Whp[rowB*5+i2]*km;
    wsB[3]=Whp[rowB*5+i3]*km; wsB[4]=Whp[rowB*5+4]*km;
    bbA = bias[((size_t)4 * 2 + dd) * 20 + rowA] * km;
    bbB = bias[((size_t)4 * 2 + dd) * 20 + rowB] * km;

    if (dd == 0) {
      const int srcbase = (1 * NB_ + blb) * T_;            // t0 = 0 forward
      scan_lds<false>(lds, srcbase * 2, BOFF + srcbase, COFF + srcbase * 2, 2, 1,
                      0, 0, 0, false,
                      wiA, wiB, bbA, bbB, wsA, wsB, vm, va,
                      c, c4, h0s, h1s, h2s, h3s, h4);
    } else {
      const int srcbase = (1 * NB_ + blb) * T_ + (T_ - 1);
      Row5 r = ld_row(lds, srcbase * 2, BOFF + srcbase, COFF + srcbase * 2);
      Pre2 pr = proj_dual(r, wiA, wiB, bbA, bbB);
      c = 0.f; c4 = 0.f; h0s = h1s = h2s = h3s = h4 = 0.f;
      recur_dual(pr.a, pr.b, wsA, wsB, vm, va, c, c4, h0s, h1s, h2s, h3s, h4);
    }
  }
  // hlast overlays the dead buf0 A-region (80 floats).
  {
    float* hl = (float*)lds;
    if (doStore) {
      const int base = (blb * 2 + dd) * 5;
      hl[base + 0] = h0s; hl[base + 1] = h1s; hl[base + 2] = h2s;
      hl[base + 3] = h3s; hl[base + 4] = h4;
    }
  }
  __syncthreads();

  // ---------------- fused FC: out[b] = hlast[b] @ Wfc^T + bfc ----------------
  if (tid < 16) {
    const int bl = tid >> 1, o = tid & 1;
    const float* hl = (const float*)lds;
    const int gb = blockIdx.x * NB_ + bl;
    float a = bfc[o];
    #pragma unroll
    for (int u = 0; u < 5; ++u) a = fmaf(hl[(bl*2+0)*5 + u], Wfc[o * 10 + u], a);
    #pragma unroll
    for (int u = 0; u < 5; ++u) a = fmaf(hl[(bl*2+1)*5 + u], Wfc[o * 10 + 5 + u], a);
    out[gb * 2 + o] = a;
  }
}

extern "C" void kernel_launch(void* const* d_in, const int* in_sizes, int n_in,
                              void* d_out, int out_size, void* d_ws, size_t ws_size,
                              hipStream_t stream) {
  (void)in_sizes; (void)n_in; (void)out_size; (void)d_ws; (void)ws_size;
  const float* x    = (const float*)d_in[0];
  const float* Wih0 = (const float*)d_in[1];
  const float* Wih  = (const float*)d_in[2];
  const float* Whh  = (const float*)d_in[3];
  const float* bias = (const float*)d_in[4];
  const float* Wfc  = (const float*)d_in[5];
  const float* bfc  = (const float*)d_in[6];
  float* out = (float*)d_out;

  dim3 grid(B_ / NB_);   // 256 blocks, 1 per CU (160KB LDS each)
  dim3 block(256);
  lstm_all<<<grid, block, 0, stream>>>(x, Wih0, Wih, Whh, bias, Wfc, bfc, out);
}

// Round 8
// 407.738 us; speedup vs baseline: 1.2117x; 1.2117x over previous
//
#include <hip/hip_runtime.h>

#define T_ 512
#define B_ 2048
#define NB_ 8                 // batches per block; grid = B_/NB_ = 256 = 1 block/CU
#define TANH_K (-2.8853900817779268f)   // -2*log2(e)

// LDS layout (dword units). Two ping-pong buffers, each 8 batches x 512 rows x
// 10 f16 cols (20 B/row), SoA-split for 8B alignment:
//   A[buf][b][t] : uint2 = cols 0-3   base AOFF, idx ((buf*8+b)*512+t)*2
//   B[buf][b][t] : u32   = cols 4-5   base BOFF, idx  (buf*8+b)*512+t
//   C[buf][b][t] : uint2 = cols 6-9   base COFF, idx ((buf*8+b)*512+t)*2
// total = 40960 dwords = 163840 B. dir0 owns cols 0-4, dir1 owns cols 5-9.
#define AOFF 0
#define BOFF 16384
#define COFF 24576

// DPP ctrl encodings (gfx9/CDNA)
#define DPP_ROW_ROR8        0x128   // lane^8  within 16-lane row
#define DPP_ROW_MIRROR      0x140   // lane^15 within 16-lane row
#define DPP_ROW_HALF_MIRROR 0x141   // lane^7  within 16-lane row

__device__ __forceinline__ float sig2(float y) {           // 1/(1+exp2(y))
  return __builtin_amdgcn_rcpf(1.0f + __builtin_amdgcn_exp2f(y));
}

template<int CTRL>
__device__ __forceinline__ float dppf(float v) {
  return __int_as_float(__builtin_amdgcn_mov_dpp(__float_as_int(v), CTRL, 0xF, 0xF, true));
}

typedef __fp16 fp16x2 __attribute__((ext_vector_type(2)));

__device__ __forceinline__ unsigned pkrtz(float a, float b) {  // 2xf32 -> packed f16
  union { fp16x2 h; unsigned u; } cv;
  cv.h = __builtin_amdgcn_cvt_pkrtz(a, b);
  return cv.u;
}

__device__ __forceinline__ float fdot2(unsigned x, unsigned w, float acc) {
  // D = x.f16[0]*w.f16[0] + x.f16[1]*w.f16[1] + acc   (v_dot2_f32_f16)
  float r;
  asm("v_dot2_f32_f16 %0, %1, %2, %3" : "=v"(r) : "v"(x), "v"(w), "v"(acc));
  return r;
}

struct Row5 { uint2 a; unsigned b; uint2 c; };
struct Pre2 { float a, b; };
struct WS {
  unsigned wpA[5], wpB[5];     // packed f16 input-weight pairs (km-scaled)
  float wsA[5], wsB[5];        // slot-permuted recurrent weights (km-scaled)
  float bbA, bbB;              // km-scaled biases
};

__device__ __forceinline__ Row5 ld_row(const unsigned* lds, int ai, int bi, int ci) {
  Row5 r;
  r.a = *(const uint2*)(lds + ai);
  r.b = lds[bi];
  r.c = *(const uint2*)(lds + ci);
  return r;
}

// Dual input projection via f16 dot2: row A (gate g of unit p), row B (gate g of unit 4).
__device__ __forceinline__ Pre2 proj_dual(const Row5& r, const WS& W) {
  float a = fdot2(r.a.x, W.wpA[0], W.bbA);
  a = fdot2(r.a.y, W.wpA[1], a);
  a = fdot2(r.b,   W.wpA[2], a);
  a = fdot2(r.c.x, W.wpA[3], a);
  a = fdot2(r.c.y, W.wpA[4], a);
  float b = fdot2(r.a.x, W.wpB[0], W.bbB);
  b = fdot2(r.a.y, W.wpB[1], b);
  b = fdot2(r.b,   W.wpB[2], b);
  b = fdot2(r.c.x, W.wpB[3], b);
  b = fdot2(r.c.y, W.wpB[4], b);
  Pre2 o; o.a = a; o.b = b; return o;
}

// One recurrent step for a 16-lane chain. Lane = 4p+g: row A = gate g of unit p,
// row B = gate g of unit 4 (redundant/identical in every quad). f32 throughout.
__device__ __forceinline__ void recur_dual(float preA, float preB, const WS& W,
    float vm, float va,
    float& c, float& c4, float& h0s, float& h1s, float& h2s, float& h3s, float& h4)
{
  const float a0 = fmaf(W.wsA[1], h1s, fmaf(W.wsA[0], h0s, preA));
  const float a1 = fmaf(W.wsA[4], h4,  fmaf(W.wsA[3], h3s, W.wsA[2] * h2s));
  const float b0 = fmaf(W.wsB[1], h1s, fmaf(W.wsB[0], h0s, preB));
  const float b1 = fmaf(W.wsB[4], h4,  fmaf(W.wsB[3], h3s, W.wsB[2] * h2s));
  const float vA = fmaf(sig2(a0 + a1), vm, va);   // sigmoid, or tanh = 2s-1
  const float vB = fmaf(sig2(b0 + b1), vm, va);
  const float ivA = dppf<0x00>(vA), fvA = dppf<0x55>(vA), gvA = dppf<0xAA>(vA), ovA = dppf<0xFF>(vA);
  const float ivB = dppf<0x00>(vB), fvB = dppf<0x55>(vB), gvB = dppf<0xAA>(vB), ovB = dppf<0xFF>(vB);
  c  = fmaf(fvA, c,  ivA * gvA);
  c4 = fmaf(fvB, c4, ivB * gvB);
  const float h = fmaf(sig2(c * TANH_K), 2.0f * ovA, -ovA);   // ov*tanh(c)
  h4            = fmaf(sig2(c4 * TANH_K), 2.0f * ovB, -ovB);
  h0s = h;
  h1s = dppf<DPP_ROW_HALF_MIRROR>(h);   // lane^7  -> unit p^1
  h2s = dppf<DPP_ROW_ROR8>(h);          // lane^8  -> unit p^2
  h3s = dppf<DPP_ROW_MIRROR>(h);        // lane^15 -> unit p^3
}

template<int DD>
__device__ __forceinline__ void emit_row(unsigned* lds, int dpair, int dsh,
    float h0s, float h1s, float h2s, float h3s, float h4) {
  unsigned v0, v1, vs;
  if constexpr (DD) { v0 = pkrtz(h1s, h2s); v1 = pkrtz(h3s, h4); vs = pkrtz(h0s, h0s); }
  else              { v0 = pkrtz(h0s, h1s); v1 = pkrtz(h2s, h3s); vs = pkrtz(h4, h4); }
  uint2 pr; pr.x = v0; pr.y = v1;
  *(uint2*)(lds + dpair) = pr;                       // A pair (d0) or C pair (d1)
  ((unsigned short*)lds)[dsh] = (unsigned short)vs;  // B.lo (d0) or B.hi (d1)
}

// LDS-input scan (layers 1..4), 4-slot software pipeline. Direction templated.
template<int DD, bool STORE>
__device__ __forceinline__ void scan_lds(unsigned* lds, int srcbase, int dstbase,
    bool doStore, const WS& W, float vm, float va,
    float& c, float& c4, float& h0s, float& h1s, float& h2s, float& h3s, float& h4)
{
  constexpr int sA = DD ? -2 : 2;
  constexpr int sB = DD ? -1 : 1;
  int sab = AOFF + srcbase * 2, sbb = BOFF + srcbase, scb = COFF + srcbase * 2;
  int dpair = (DD ? COFF : AOFF) + dstbase * 2;
  int dsh   = (BOFF + dstbase) * 2 + DD;
  Row5 p_[4]; Pre2 pre[4];
  #pragma unroll
  for (int k = 0; k < 4; ++k) { p_[k] = ld_row(lds, sab, sbb, scb); sab += sA; sbb += sB; scb += sA; }
  #pragma unroll
  for (int k = 0; k < 4; ++k) pre[k] = proj_dual(p_[k], W);
  #pragma unroll
  for (int k = 0; k < 4; ++k) { p_[k] = ld_row(lds, sab, sbb, scb); sab += sA; sbb += sB; scb += sA; }
  c = 0.f; c4 = 0.f; h0s = h1s = h2s = h3s = h4 = 0.f;
  for (int tt = 0; tt + 8 < T_; tt += 4) {
    #pragma unroll
    for (int j = 0; j < 4; ++j) {
      recur_dual(pre[j].a, pre[j].b, W, vm, va, c, c4, h0s, h1s, h2s, h3s, h4);
      if constexpr (STORE) {
        if (doStore) emit_row<DD>(lds, dpair, dsh, h0s, h1s, h2s, h3s, h4);
        dpair += sA; dsh += 2 * sB;
      }
      pre[j] = proj_dual(p_[j], W);
      p_[j] = ld_row(lds, sab, sbb, scb); sab += sA; sbb += sB; scb += sA;
    }
  }
  #pragma unroll
  for (int j = 0; j < 4; ++j) {     // steps T-8..T-5
    recur_dual(pre[j].a, pre[j].b, W, vm, va, c, c4, h0s, h1s, h2s, h3s, h4);
    if constexpr (STORE) {
      if (doStore) emit_row<DD>(lds, dpair, dsh, h0s, h1s, h2s, h3s, h4);
      dpair += sA; dsh += 2 * sB;
    }
    pre[j] = proj_dual(p_[j], W);
  }
  #pragma unroll
  for (int j = 0; j < 4; ++j) {     // steps T-4..T-1
    recur_dual(pre[j].a, pre[j].b, W, vm, va, c, c4, h0s, h1s, h2s, h3s, h4);
    if constexpr (STORE) {
      if (doStore) emit_row<DD>(lds, dpair, dsh, h0s, h1s, h2s, h3s, h4);
      dpair += sA; dsh += 2 * sB;
    }
  }
}

// Layer-0 scan: f32 global input (width 2), packed to f16 + dot2. 8-deep prefetch.
template<int DD>
__device__ __forceinline__ void scan0(const float* src, unsigned* lds, int dstbase,
    bool doStore, const WS& W, float vm, float va)
{
  constexpr int sstep = DD ? -2 : 2;
  constexpr int sA = DD ? -2 : 2;
  constexpr int sB = DD ? -1 : 1;
  int dpair = (DD ? COFF : AOFF) + dstbase * 2;
  int dsh   = (BOFF + dstbase) * 2 + DD;
  float2 p_[8]; Pre2 pre[8];
  #pragma unroll
  for (int k = 0; k < 8; ++k) p_[k] = *(const float2*)(src + k * sstep);
  #pragma unroll
  for (int k = 0; k < 8; ++k) {
    const unsigned xp = pkrtz(p_[k].x, p_[k].y);
    pre[k].a = fdot2(xp, W.wpA[0], W.bbA);
    pre[k].b = fdot2(xp, W.wpB[0], W.bbB);
  }
  #pragma unroll
  for (int k = 0; k < 8; ++k) p_[k] = *(const float2*)(src + (8 + k) * sstep);
  const float* lp = src + 16 * sstep;
  float c = 0.f, c4 = 0.f, h0s = 0.f, h1s = 0.f, h2s = 0.f, h3s = 0.f, h4 = 0.f;
  for (int tt = 0; tt + 16 < T_; tt += 8) {
    #pragma unroll
    for (int j = 0; j < 8; ++j) {
      recur_dual(pre[j].a, pre[j].b, W, vm, va, c, c4, h0s, h1s, h2s, h3s, h4);
      if (doStore) emit_row<DD>(lds, dpair, dsh, h0s, h1s, h2s, h3s, h4);
      dpair += sA; dsh += 2 * sB;
      const unsigned xp = pkrtz(p_[j].x, p_[j].y);
      pre[j].a = fdot2(xp, W.wpA[0], W.bbA);
      pre[j].b = fdot2(xp, W.wpB[0], W.bbB);
      p_[j] = *(const float2*)lp; lp += sstep;
    }
  }
  #pragma unroll
  for (int j = 0; j < 8; ++j) {
    recur_dual(pre[j].a, pre[j].b, W, vm, va, c, c4, h0s, h1s, h2s, h3s, h4);
    if (doStore) emit_row<DD>(lds, dpair, dsh, h0s, h1s, h2s, h3s, h4);
    dpair += sA; dsh += 2 * sB;
    const unsigned xp = pkrtz(p_[j].x, p_[j].y);
    pre[j].a = fdot2(xp, W.wpA[0], W.bbA);
    pre[j].b = fdot2(xp, W.wpB[0], W.bbB);
  }
  #pragma unroll
  for (int j = 0; j < 8; ++j) {
    recur_dual(pre[j].a, pre[j].b, W, vm, va, c, c4, h0s, h1s, h2s, h3s, h4);
    if (doStore) emit_row<DD>(lds, dpair, dsh, h0s, h1s, h2s, h3s, h4);
    dpair += sA; dsh += 2 * sB;
  }
}

__device__ __forceinline__ void load_rec(WS& W, const float* Whp, const float* bp,
    int rowA, int rowB, int p, int i1, int i2, int i3, float km) {
  W.wsA[0] = Whp[rowA*5+p]*km;  W.wsA[1] = Whp[rowA*5+i1]*km; W.wsA[2] = Whp[rowA*5+i2]*km;
  W.wsA[3] = Whp[rowA*5+i3]*km; W.wsA[4] = Whp[rowA*5+4]*km;
  W.wsB[0] = Whp[rowB*5+p]*km;  W.wsB[1] = Whp[rowB*5+i1]*km; W.wsB[2] = Whp[rowB*5+i2]*km;
  W.wsB[3] = Whp[rowB*5+i3]*km; W.wsB[4] = Whp[rowB*5+4]*km;
  W.bbA = bp[rowA]*km; W.bbB = bp[rowB]*km;
}

__global__ __launch_bounds__(256) void lstm_all(
    const float* __restrict__ x, const float* __restrict__ Wih0,
    const float* __restrict__ Wih, const float* __restrict__ Whh,
    const float* __restrict__ bias, const float* __restrict__ Wfc,
    const float* __restrict__ bfc, float* __restrict__ out)
{
  __shared__ __align__(16) unsigned lds[40960];   // 163840 B = gfx950 LDS max

  const int tid  = threadIdx.x;
  const int lane = tid & 63;
  const int wave = tid >> 6;
  const int cw   = lane >> 4;          // chain within wave: 0..3
  const int sub  = lane & 15;
  const int p    = sub >> 2;           // hidden unit (quad) 0..3
  const int g    = sub & 3;            // gate 0=i,1=f,2=g,3=o
  const int rowA = g * 5 + p;
  const int rowB = g * 5 + 4;
  const int dd   = wave & 1;           // direction, WAVE-UNIFORM
  const int blb  = cw + (wave >> 1) * 4;   // block-local batch 0..7
  const int babs = blockIdx.x * NB_ + blb;

  const int i1 = p ^ 1, i2 = p ^ 2, i3 = p ^ 3;

  const float LOG2E = 1.4426950408889634f;
  const float km = (g == 2) ? (-2.0f * LOG2E) : (-LOG2E);
  const float vm = (g == 2) ? 2.0f : 1.0f;
  const float va = (g == 2) ? -1.0f : 0.0f;

  const bool doStore = (sub == 0);
  const int t0 = dd ? (T_ - 1) : 0;

  WS W;
  float c, c4, h0s, h1s, h2s, h3s, h4;

  // ---------------- layer 0 (f32 x, width 2) -> buf0 ----------------
  {
    const float* W0 = Wih0 + (size_t)dd * 20 * 2;
    W.wpA[0] = pkrtz(W0[rowA*2+0]*km, W0[rowA*2+1]*km);
    W.wpB[0] = pkrtz(W0[rowB*2+0]*km, W0[rowB*2+1]*km);
    load_rec(W, Whh + (size_t)dd * 20 * 5, bias + (size_t)dd * 20,
             rowA, rowB, p, i1, i2, i3, km);
    const int dstbase = blb * T_ + t0;                    // buf0
    const float* src0 = x + ((size_t)babs * T_ + t0) * 2;
    if (dd == 0) scan0<0>(src0, lds, dstbase, doStore, W, vm, va);
    else         scan0<1>(src0, lds, dstbase, doStore, W, vm, va);
  }
  __syncthreads();

  // ---------------- layers 1..3 ----------------
  for (int l = 1; l < 4; ++l) {
    const float* Wip = Wih + ((size_t)(l - 1) * 2 + dd) * 20 * 10;
    #pragma unroll
    for (int k = 0; k < 5; ++k) {
      W.wpA[k] = pkrtz(Wip[rowA*10+2*k]*km, Wip[rowA*10+2*k+1]*km);
      W.wpB[k] = pkrtz(Wip[rowB*10+2*k]*km, Wip[rowB*10+2*k+1]*km);
    }
    load_rec(W, Whh + ((size_t)l * 2 + dd) * 20 * 5, bias + ((size_t)l * 2 + dd) * 20,
             rowA, rowB, p, i1, i2, i3, km);
    const int sbuf = (l + 1) & 1, dbuf = l & 1;           // L1:0->1 L2:1->0 L3:0->1
    const int srcbase = (sbuf * NB_ + blb) * T_ + t0;
    const int dstbase = (dbuf * NB_ + blb) * T_ + t0;
    if (dd == 0) scan_lds<0, true>(lds, srcbase, dstbase, doStore, W, vm, va,
                                   c, c4, h0s, h1s, h2s, h3s, h4);
    else         scan_lds<1, true>(lds, srcbase, dstbase, doStore, W, vm, va,
                                   c, c4, h0s, h1s, h2s, h3s, h4);
    __syncthreads();
  }

  // ---------------- layer 4 (reads buf1): fwd full scan, bwd 1 step ----------------
  {
    const float* Wip = Wih + ((size_t)3 * 2 + dd) * 20 * 10;
    #pragma unroll
    for (int k = 0; k < 5; ++k) {
      W.wpA[k] = pkrtz(Wip[rowA*10+2*k]*km, Wip[rowA*10+2*k+1]*km);
      W.wpB[k] = pkrtz(Wip[rowB*10+2*k]*km, Wip[rowB*10+2*k+1]*km);
    }
    load_rec(W, Whh + ((size_t)4 * 2 + dd) * 20 * 5, bias + ((size_t)4 * 2 + dd) * 20,
             rowA, rowB, p, i1, i2, i3, km);

    if (dd == 0) {
      const int srcbase = (1 * NB_ + blb) * T_;            // forward from t=0
      scan_lds<0, false>(lds, srcbase, 0, false, W, vm, va,
                         c, c4, h0s, h1s, h2s, h3s, h4);
    } else {
      const int srcbase = (1 * NB_ + blb) * T_ + (T_ - 1);
      Row5 r = ld_row(lds, AOFF + srcbase * 2, BOFF + srcbase, COFF + srcbase * 2);
      Pre2 pr = proj_dual(r, W);
      c = 0.f; c4 = 0.f; h0s = h1s = h2s = h3s = h4 = 0.f;
      recur_dual(pr.a, pr.b, W, vm, va, c, c4, h0s, h1s, h2s, h3s, h4);
    }
  }
  // hlast overlays the dead buf0 A-region (80 floats).
  {
    float* hl = (float*)lds;
    if (doStore) {
      const int base = (blb * 2 + dd) * 5;
      hl[base + 0] = h0s; hl[base + 1] = h1s; hl[base + 2] = h2s;
      hl[base + 3] = h3s; hl[base + 4] = h4;
    }
  }
  __syncthreads();

  // ---------------- fused FC: out[b] = hlast[b] @ Wfc^T + bfc ----------------
  if (tid < 16) {
    const int bl = tid >> 1, o = tid & 1;
    const float* hl = (const float*)lds;
    const int gb = blockIdx.x * NB_ + bl;
    float a = bfc[o];
    #pragma unroll
    for (int u = 0; u < 5; ++u) a = fmaf(hl[(bl*2+0)*5 + u], Wfc[o * 10 + u], a);
    #pragma unroll
    for (int u = 0; u < 5; ++u) a = fmaf(hl[(bl*2+1)*5 + u], Wfc[o * 10 + 5 + u], a);
    out[gb * 2 + o] = a;
  }
}

extern "C" void kernel_launch(void* const* d_in, const int* in_sizes, int n_in,
                              void* d_out, int out_size, void* d_ws, size_t ws_size,
                              hipStream_t stream) {
  (void)in_sizes; (void)n_in; (void)out_size; (void)d_ws; (void)ws_size;
  const float* x    = (const float*)d_in[0];
  const float* Wih0 = (const float*)d_in[1];
  const float* Wih  = (const float*)d_in[2];
  const float* Whh  = (const float*)d_in[3];
  const float* bias = (const float*)d_in[4];
  const float* Wfc  = (const float*)d_in[5];
  const float* bfc  = (const float*)d_in[6];
  float* out = (float*)d_out;

  dim3 grid(B_ / NB_);   // 256 blocks, 1 per CU
  dim3 block(256);
  lstm_all<<<grid, block, 0, stream>>>(x, Wih0, Wih, Whh, bias, Wfc, bfc, out);
}

// Round 9
// 389.880 us; speedup vs baseline: 1.2672x; 1.0458x over previous
//
#include <hip/hip_runtime.h>

#define T_ 512
#define B_ 2048
#define NB_ 8                 // batches per block; grid = B_/NB_ = 256 = 1 block/CU
#define TANH_K (-2.8853900817779268f)   // -2*log2(e)

// LDS layout, batch-innermost for bank-conflict freedom.
// Per (buf,t) slot = 160 B:  A[8 batches]x8B | C[8]x8B | B[8]x4B
//   A = f16 cols 0-3 (dir0 h0..h3), B.lo = col4 (dir0 h4), B.hi = col5 (dir1 h0),
//   C = cols 6-9 (dir1 h1..h4).
// pA(buf,t,b) = buf*81920 + t*160 + b*8   (A at +0, C at +64 immediate)
// pB(buf,t,b) = buf*81920 + t*160 + 128 + b*4
// Within a wave: 4 chains at consecutive b -> addrs differ by 8B -> distinct banks.
#define BUFOFF 81920
#define SLOT   160

// DPP ctrl encodings (gfx9/CDNA)
#define DPP_ROW_ROR8        0x128   // lane^8  within 16-lane row
#define DPP_ROW_MIRROR      0x140   // lane^15 within 16-lane row
#define DPP_ROW_HALF_MIRROR 0x141   // lane^7  within 16-lane row

__device__ __forceinline__ float sig2(float y) {           // 1/(1+exp2(y))
  return __builtin_amdgcn_rcpf(1.0f + __builtin_amdgcn_exp2f(y));
}

template<int CTRL>
__device__ __forceinline__ float dppf(float v) {
  return __int_as_float(__builtin_amdgcn_mov_dpp(__float_as_int(v), CTRL, 0xF, 0xF, true));
}

typedef __fp16 fp16x2 __attribute__((ext_vector_type(2)));

__device__ __forceinline__ unsigned pkrtz(float a, float b) {  // 2xf32 -> packed f16
  union { fp16x2 h; unsigned u; } cv;
  cv.h = __builtin_amdgcn_cvt_pkrtz(a, b);
  return cv.u;
}

__device__ __forceinline__ float fdot2(unsigned x, unsigned w, float acc) {
  // D = x.f16[0]*w.f16[0] + x.f16[1]*w.f16[1] + acc   (v_dot2_f32_f16)
  float r;
  asm("v_dot2_f32_f16 %0, %1, %2, %3" : "=v"(r) : "v"(x), "v"(w), "v"(acc));
  return r;
}

struct Row5 { uint2 a; unsigned b; uint2 c; };
struct Pre2 { float a, b; };
struct WS {
  unsigned wpA[5], wpB[5];     // packed f16 input-weight pairs (km-scaled)
  float wsA[5], wsB[5];        // slot-permuted recurrent weights (km-scaled)
  float bbA, bbB;              // km-scaled biases
};

__device__ __forceinline__ Row5 ld_row(const unsigned char* ldsb, int pA, int pB) {
  Row5 r;
  r.a = *(const uint2*)(ldsb + pA);        // ds_read_b64, offset 0
  r.c = *(const uint2*)(ldsb + pA + 64);   // ds_read_b64, offset 64 (immediate)
  r.b = *(const unsigned*)(ldsb + pB);     // ds_read_b32
  return r;
}

// Dual input projection via f16 dot2: row A (gate g of unit p), row B (gate g of unit 4).
__device__ __forceinline__ Pre2 proj_dual(const Row5& r, const WS& W) {
  float a = fdot2(r.a.x, W.wpA[0], W.bbA);
  a = fdot2(r.a.y, W.wpA[1], a);
  a = fdot2(r.b,   W.wpA[2], a);
  a = fdot2(r.c.x, W.wpA[3], a);
  a = fdot2(r.c.y, W.wpA[4], a);
  float b = fdot2(r.a.x, W.wpB[0], W.bbB);
  b = fdot2(r.a.y, W.wpB[1], b);
  b = fdot2(r.b,   W.wpB[2], b);
  b = fdot2(r.c.x, W.wpB[3], b);
  b = fdot2(r.c.y, W.wpB[4], b);
  Pre2 o; o.a = a; o.b = b; return o;
}

// One recurrent step for a 16-lane chain. Lane = 4p+g: row A = gate g of unit p,
// row B = gate g of unit 4 (redundant/identical in every quad). f32 throughout.
__device__ __forceinline__ void recur_dual(float preA, float preB, const WS& W,
    float vm, float va,
    float& c, float& c4, float& h0s, float& h1s, float& h2s, float& h3s, float& h4)
{
  const float a0 = fmaf(W.wsA[1], h1s, fmaf(W.wsA[0], h0s, preA));
  const float a1 = fmaf(W.wsA[4], h4,  fmaf(W.wsA[3], h3s, W.wsA[2] * h2s));
  const float b0 = fmaf(W.wsB[1], h1s, fmaf(W.wsB[0], h0s, preB));
  const float b1 = fmaf(W.wsB[4], h4,  fmaf(W.wsB[3], h3s, W.wsB[2] * h2s));
  const float vA = fmaf(sig2(a0 + a1), vm, va);   // sigmoid, or tanh = 2s-1
  const float vB = fmaf(sig2(b0 + b1), vm, va);
  const float ivA = dppf<0x00>(vA), fvA = dppf<0x55>(vA), gvA = dppf<0xAA>(vA), ovA = dppf<0xFF>(vA);
  const float ivB = dppf<0x00>(vB), fvB = dppf<0x55>(vB), gvB = dppf<0xAA>(vB), ovB = dppf<0xFF>(vB);
  c  = fmaf(fvA, c,  ivA * gvA);
  c4 = fmaf(fvB, c4, ivB * gvB);
  const float h = fmaf(sig2(c * TANH_K), 2.0f * ovA, -ovA);   // ov*tanh(c)
  h4            = fmaf(sig2(c4 * TANH_K), 2.0f * ovB, -ovB);
  h0s = h;
  h1s = dppf<DPP_ROW_HALF_MIRROR>(h);   // lane^7  -> unit p^1
  h2s = dppf<DPP_ROW_ROR8>(h);          // lane^8  -> unit p^2
  h3s = dppf<DPP_ROW_MIRROR>(h);        // lane^15 -> unit p^3
}

template<int DD>
__device__ __forceinline__ void emit_row(unsigned char* ldsb, int dpA, int dpB,
    float h0s, float h1s, float h2s, float h3s, float h4) {
  if constexpr (DD) {
    uint2 pr; pr.x = pkrtz(h1s, h2s); pr.y = pkrtz(h3s, h4);
    *(uint2*)(ldsb + dpA + 64) = pr;                                  // C pair
    *(unsigned short*)(ldsb + dpB + 2) = (unsigned short)pkrtz(h0s, h0s); // B.hi
  } else {
    uint2 pr; pr.x = pkrtz(h0s, h1s); pr.y = pkrtz(h2s, h3s);
    *(uint2*)(ldsb + dpA) = pr;                                       // A pair
    *(unsigned short*)(ldsb + dpB) = (unsigned short)pkrtz(h4, h4);   // B.lo
  }
}

// LDS-input scan (layers 1..4), 8-slot software pipeline. Direction templated.
template<int DD, bool STORE>
__device__ __forceinline__ void scan_lds(unsigned char* ldsb, int pA, int pB,
    int dpA, int dpB, bool doStore, const WS& W, float vm, float va,
    float& c, float& c4, float& h0s, float& h1s, float& h2s, float& h3s, float& h4)
{
  constexpr int s = DD ? -SLOT : SLOT;
  Row5 p_[8]; Pre2 pre[8];
  #pragma unroll
  for (int k = 0; k < 8; ++k) { p_[k] = ld_row(ldsb, pA, pB); pA += s; pB += s; }
  #pragma unroll
  for (int k = 0; k < 8; ++k) pre[k] = proj_dual(p_[k], W);
  #pragma unroll
  for (int k = 0; k < 8; ++k) { p_[k] = ld_row(ldsb, pA, pB); pA += s; pB += s; }
  c = 0.f; c4 = 0.f; h0s = h1s = h2s = h3s = h4 = 0.f;
  for (int tt = 0; tt + 16 < T_; tt += 8) {
    #pragma unroll
    for (int j = 0; j < 8; ++j) {
      recur_dual(pre[j].a, pre[j].b, W, vm, va, c, c4, h0s, h1s, h2s, h3s, h4);
      if constexpr (STORE) {
        if (doStore) emit_row<DD>(ldsb, dpA, dpB, h0s, h1s, h2s, h3s, h4);
        dpA += s; dpB += s;
      }
      pre[j] = proj_dual(p_[j], W);
      p_[j] = ld_row(ldsb, pA, pB); pA += s; pB += s;
    }
  }
  #pragma unroll
  for (int j = 0; j < 8; ++j) {     // steps T-16..T-9, refill pre from last rows
    recur_dual(pre[j].a, pre[j].b, W, vm, va, c, c4, h0s, h1s, h2s, h3s, h4);
    if constexpr (STORE) {
      if (doStore) emit_row<DD>(ldsb, dpA, dpB, h0s, h1s, h2s, h3s, h4);
      dpA += s; dpB += s;
    }
    pre[j] = proj_dual(p_[j], W);
  }
  #pragma unroll
  for (int j = 0; j < 8; ++j) {     // steps T-8..T-1
    recur_dual(pre[j].a, pre[j].b, W, vm, va, c, c4, h0s, h1s, h2s, h3s, h4);
    if constexpr (STORE) {
      if (doStore) emit_row<DD>(ldsb, dpA, dpB, h0s, h1s, h2s, h3s, h4);
      dpA += s; dpB += s;
    }
  }
}

// Layer-0 scan: f32 global input (width 2), packed to f16 + dot2. 8-deep prefetch.
template<int DD>
__device__ __forceinline__ void scan0(const float* src, unsigned char* ldsb,
    int dpA, int dpB, bool doStore, const WS& W, float vm, float va)
{
  constexpr int sstep = DD ? -2 : 2;
  constexpr int s = DD ? -SLOT : SLOT;
  float2 p_[8]; Pre2 pre[8];
  #pragma unroll
  for (int k = 0; k < 8; ++k) p_[k] = *(const float2*)(src + k * sstep);
  #pragma unroll
  for (int k = 0; k < 8; ++k) {
    const unsigned xp = pkrtz(p_[k].x, p_[k].y);
    pre[k].a = fdot2(xp, W.wpA[0], W.bbA);
    pre[k].b = fdot2(xp, W.wpB[0], W.bbB);
  }
  #pragma unroll
  for (int k = 0; k < 8; ++k) p_[k] = *(const float2*)(src + (8 + k) * sstep);
  const float* lp = src + 16 * sstep;
  float c = 0.f, c4 = 0.f, h0s = 0.f, h1s = 0.f, h2s = 0.f, h3s = 0.f, h4 = 0.f;
  for (int tt = 0; tt + 16 < T_; tt += 8) {
    #pragma unroll
    for (int j = 0; j < 8; ++j) {
      recur_dual(pre[j].a, pre[j].b, W, vm, va, c, c4, h0s, h1s, h2s, h3s, h4);
      if (doStore) emit_row<DD>(ldsb, dpA, dpB, h0s, h1s, h2s, h3s, h4);
      dpA += s; dpB += s;
      const unsigned xp = pkrtz(p_[j].x, p_[j].y);
      pre[j].a = fdot2(xp, W.wpA[0], W.bbA);
      pre[j].b = fdot2(xp, W.wpB[0], W.bbB);
      p_[j] = *(const float2*)lp; lp += sstep;
    }
  }
  #pragma unroll
  for (int j = 0; j < 8; ++j) {
    recur_dual(pre[j].a, pre[j].b, W, vm, va, c, c4, h0s, h1s, h2s, h3s, h4);
    if (doStore) emit_row<DD>(ldsb, dpA, dpB, h0s, h1s, h2s, h3s, h4);
    dpA += s; dpB += s;
    const unsigned xp = pkrtz(p_[j].x, p_[j].y);
    pre[j].a = fdot2(xp, W.wpA[0], W.bbA);
    pre[j].b = fdot2(xp, W.wpB[0], W.bbB);
  }
  #pragma unroll
  for (int j = 0; j < 8; ++j) {
    recur_dual(pre[j].a, pre[j].b, W, vm, va, c, c4, h0s, h1s, h2s, h3s, h4);
    if (doStore) emit_row<DD>(ldsb, dpA, dpB, h0s, h1s, h2s, h3s, h4);
    dpA += s; dpB += s;
  }
}

__device__ __forceinline__ void load_rec(WS& W, const float* Whp, const float* bp,
    int rowA, int rowB, int p, int i1, int i2, int i3, float km) {
  W.wsA[0] = Whp[rowA*5+p]*km;  W.wsA[1] = Whp[rowA*5+i1]*km; W.wsA[2] = Whp[rowA*5+i2]*km;
  W.wsA[3] = Whp[rowA*5+i3]*km; W.wsA[4] = Whp[rowA*5+4]*km;
  W.wsB[0] = Whp[rowB*5+p]*km;  W.wsB[1] = Whp[rowB*5+i1]*km; W.wsB[2] = Whp[rowB*5+i2]*km;
  W.wsB[3] = Whp[rowB*5+i3]*km; W.wsB[4] = Whp[rowB*5+4]*km;
  W.bbA = bp[rowA]*km; W.bbB = bp[rowB]*km;
}

__global__ __launch_bounds__(256) void lstm_all(
    const float* __restrict__ x, const float* __restrict__ Wih0,
    const float* __restrict__ Wih, const float* __restrict__ Whh,
    const float* __restrict__ bias, const float* __restrict__ Wfc,
    const float* __restrict__ bfc, float* __restrict__ out)
{
  __shared__ __align__(16) unsigned char ldsb[163840];   // gfx950 LDS max

  const int tid  = threadIdx.x;
  const int lane = tid & 63;
  const int wave = tid >> 6;
  const int cw   = lane >> 4;          // chain within wave: 0..3
  const int sub  = lane & 15;
  const int p    = sub >> 2;           // hidden unit (quad) 0..3
  const int g    = sub & 3;            // gate 0=i,1=f,2=g,3=o
  const int rowA = g * 5 + p;
  const int rowB = g * 5 + 4;
  const int dd   = wave & 1;           // direction, WAVE-UNIFORM
  const int blb  = cw + (wave >> 1) * 4;   // block-local batch 0..7
  const int babs = blockIdx.x * NB_ + blb;

  const int i1 = p ^ 1, i2 = p ^ 2, i3 = p ^ 3;

  const float LOG2E = 1.4426950408889634f;
  const float km = (g == 2) ? (-2.0f * LOG2E) : (-LOG2E);
  const float vm = (g == 2) ? 2.0f : 1.0f;
  const float va = (g == 2) ? -1.0f : 0.0f;

  const bool doStore = (sub == 0);
  const int t0 = dd ? (T_ - 1) : 0;
  const int slotA = blb * 8;           // byte offset of this batch's A slot within (buf,t)
  const int slotB = 128 + blb * 4;

  WS W;
  float c, c4, h0s, h1s, h2s, h3s, h4;

  // ---------------- layer 0 (f32 x, width 2) -> buf0 ----------------
  {
    const float* W0 = Wih0 + (size_t)dd * 20 * 2;
    W.wpA[0] = pkrtz(W0[rowA*2+0]*km, W0[rowA*2+1]*km);
    W.wpB[0] = pkrtz(W0[rowB*2+0]*km, W0[rowB*2+1]*km);
    load_rec(W, Whh + (size_t)dd * 20 * 5, bias + (size_t)dd * 20,
             rowA, rowB, p, i1, i2, i3, km);
    const int dpA = t0 * SLOT + slotA;            // buf0
    const int dpB = t0 * SLOT + slotB;
    const float* src0 = x + ((size_t)babs * T_ + t0) * 2;
    if (dd == 0) scan0<0>(src0, ldsb, dpA, dpB, doStore, W, vm, va);
    else         scan0<1>(src0, ldsb, dpA, dpB, doStore, W, vm, va);
  }
  __syncthreads();

  // ---------------- layers 1..3 ----------------
  for (int l = 1; l < 4; ++l) {
    const float* Wip = Wih + ((size_t)(l - 1) * 2 + dd) * 20 * 10;
    #pragma unroll
    for (int k = 0; k < 5; ++k) {
      W.wpA[k] = pkrtz(Wip[rowA*10+2*k]*km, Wip[rowA*10+2*k+1]*km);
      W.wpB[k] = pkrtz(Wip[rowB*10+2*k]*km, Wip[rowB*10+2*k+1]*km);
    }
    load_rec(W, Whh + ((size_t)l * 2 + dd) * 20 * 5, bias + ((size_t)l * 2 + dd) * 20,
             rowA, rowB, p, i1, i2, i3, km);
    const int sbuf = (l + 1) & 1, dbuf = l & 1;           // L1:0->1 L2:1->0 L3:0->1
    const int pA  = sbuf * BUFOFF + t0 * SLOT + slotA;
    const int pB  = sbuf * BUFOFF + t0 * SLOT + slotB;
    const int dpA = dbuf * BUFOFF + t0 * SLOT + slotA;
    const int dpB = dbuf * BUFOFF + t0 * SLOT + slotB;
    if (dd == 0) scan_lds<0, true>(ldsb, pA, pB, dpA, dpB, doStore, W, vm, va,
                                   c, c4, h0s, h1s, h2s, h3s, h4);
    else         scan_lds<1, true>(ldsb, pA, pB, dpA, dpB, doStore, W, vm, va,
                                   c, c4, h0s, h1s, h2s, h3s, h4);
    __syncthreads();
  }

  // ---------------- layer 4 (reads buf1): fwd full scan, bwd 1 step ----------------
  {
    const float* Wip = Wih + ((size_t)3 * 2 + dd) * 20 * 10;
    #pragma unroll
    for (int k = 0; k < 5; ++k) {
      W.wpA[k] = pkrtz(Wip[rowA*10+2*k]*km, Wip[rowA*10+2*k+1]*km);
      W.wpB[k] = pkrtz(Wip[rowB*10+2*k]*km, Wip[rowB*10+2*k+1]*km);
    }
    load_rec(W, Whh + ((size_t)4 * 2 + dd) * 20 * 5, bias + ((size_t)4 * 2 + dd) * 20,
             rowA, rowB, p, i1, i2, i3, km);

    if (dd == 0) {
      const int pA = BUFOFF + slotA;                       // forward from t=0
      const int pB = BUFOFF + slotB;
      scan_lds<0, false>(ldsb, pA, pB, 0, 0, false, W, vm, va,
                         c, c4, h0s, h1s, h2s, h3s, h4);
    } else {
      const int pA = BUFOFF + (T_ - 1) * SLOT + slotA;
      const int pB = BUFOFF + (T_ - 1) * SLOT + slotB;
      Row5 r = ld_row(ldsb, pA, pB);
      Pre2 pr = proj_dual(r, W);
      c = 0.f; c4 = 0.f; h0s = h1s = h2s = h3s = h4 = 0.f;
      recur_dual(pr.a, pr.b, W, vm, va, c, c4, h0s, h1s, h2s, h3s, h4);
    }
  }
  // hlast overlays the dead buf0 head (80 floats = 320 B).
  {
    float* hl = (float*)ldsb;
    if (doStore) {
      const int base = (blb * 2 + dd) * 5;
      hl[base + 0] = h0s; hl[base + 1] = h1s; hl[base + 2] = h2s;
      hl[base + 3] = h3s; hl[base + 4] = h4;
    }
  }
  __syncthreads();

  // ---------------- fused FC: out[b] = hlast[b] @ Wfc^T + bfc ----------------
  if (tid < 16) {
    const int bl = tid >> 1, o = tid & 1;
    const float* hl = (const float*)ldsb;
    const int gb = blockIdx.x * NB_ + bl;
    float a = bfc[o];
    #pragma unroll
    for (int u = 0; u < 5; ++u) a = fmaf(hl[(bl*2+0)*5 + u], Wfc[o * 10 + u], a);
    #pragma unroll
    for (int u = 0; u < 5; ++u) a = fmaf(hl[(bl*2+1)*5 + u], Wfc[o * 10 + 5 + u], a);
    out[gb * 2 + o] = a;
  }
}

extern "C" void kernel_launch(void* const* d_in, const int* in_sizes, int n_in,
                              void* d_out, int out_size, void* d_ws, size_t ws_size,
                              hipStream_t stream) {
  (void)in_sizes; (void)n_in; (void)out_size; (void)d_ws; (void)ws_size;
  const float* x    = (const float*)d_in[0];
  const float* Wih0 = (const float*)d_in[1];
  const float* Wih  = (const float*)d_in[2];
  const float* Whh  = (const float*)d_in[3];
  const float* bias = (const float*)d_in[4];
  const float* Wfc  = (const float*)d_in[5];
  const float* bfc  = (const float*)d_in[6];
  float* out = (float*)d_out;

  dim3 grid(B_ / NB_);   // 256 blocks, 1 per CU
  dim3 block(256);
  lstm_all<<<grid, block, 0, stream>>>(x, Wih0, Wih, Whh, bias, Wfc, bfc, out);
}